// Round 1
// baseline (50469.250 us; speedup 1.0000x reference)
//
#include <hip/hip_runtime.h>
#include <hip/hip_bf16.h>
#include <math.h>

// Problem dims (fixed by reference)
#define BATCH 1024
#define DIN   256
#define DH    512
#define DH2   1024
#define DOUT  128
#define NLAYERS 5
#define RKSTEPS 16   // fixed-step RK4 steps per ODE layer

// GEMM tile config
#define BM 64
#define BN 64
#define BK 16

enum { EM_PLAIN=0, EM_TANH=1, EM_TANH_RES=2, EM_RK_FIRST=3, EM_RK_MID=4, EM_RK_LAST=5 };

// C[M,N] = epilogue(A[M,K] @ B[K,N] + bias[N])
// RK modes operate on [M,N]-shaped state buffers (res=y_base, acc, ynext).
__global__ __launch_bounds__(256) void gemm_fused(
    const float* __restrict__ A, const float* __restrict__ B,
    const float* __restrict__ bias, float* __restrict__ C,
    const float* __restrict__ res, float* __restrict__ acc,
    float* __restrict__ ynext,
    int M, int N, int K, int emode, float wk, float hcoef)
{
    __shared__ float As[BK][BM];
    __shared__ float Bs[BK][BN];
    const int tid = threadIdx.x;
    const int tx = tid & 15;        // 0..15 (cols)
    const int ty = tid >> 4;        // 0..15 (rows)
    const int m0 = blockIdx.y * BM;
    const int n0 = blockIdx.x * BN;

    float accv[4][4];
    #pragma unroll
    for (int i = 0; i < 4; ++i)
        #pragma unroll
        for (int j = 0; j < 4; ++j) accv[i][j] = 0.0f;

    for (int k0 = 0; k0 < K; k0 += BK) {
        // Load A tile (64 rows x 16 k) -> As[k][m]; each thread: one float4 along k
        {
            const int e = tid * 4;
            const int m = e >> 4;       // e / BK
            const int k = e & (BK - 1); // e % BK
            const float4 a4 = *(const float4*)&A[(size_t)(m0 + m) * K + k0 + k];
            As[k + 0][m] = a4.x;
            As[k + 1][m] = a4.y;
            As[k + 2][m] = a4.z;
            As[k + 3][m] = a4.w;
        }
        // Load B tile (16 k x 64 cols) -> Bs[k][n]; each thread: one float4 along n
        {
            const int e = tid * 4;
            const int k = e >> 6;       // e / BN
            const int n = e & (BN - 1); // e % BN
            const float4 b4 = *(const float4*)&B[(size_t)(k0 + k) * N + n0 + n];
            *(float4*)&Bs[k][n] = b4;
        }
        __syncthreads();
        #pragma unroll
        for (int kk = 0; kk < BK; ++kk) {
            float a[4], b[4];
            *(float4*)a = *(const float4*)&As[kk][ty * 4];
            *(float4*)b = *(const float4*)&Bs[kk][tx * 4];
            #pragma unroll
            for (int i = 0; i < 4; ++i)
                #pragma unroll
                for (int j = 0; j < 4; ++j)
                    accv[i][j] = fmaf(a[i], b[j], accv[i][j]);
        }
        __syncthreads();
    }

    const int r0 = m0 + ty * 4;
    const int c0 = n0 + tx * 4;
    #pragma unroll
    for (int i = 0; i < 4; ++i) {
        const int r = r0 + i;
        #pragma unroll
        for (int j = 0; j < 4; ++j) {
            const int c = c0 + j;
            const size_t idx = (size_t)r * N + c;
            float z = accv[i][j] + bias[c];
            if (emode == EM_PLAIN) {
                C[idx] = z;
            } else if (emode == EM_TANH) {
                C[idx] = tanhf(z);
            } else if (emode == EM_TANH_RES) {
                C[idx] = tanhf(z) + res[idx];
            } else if (emode == EM_RK_FIRST) {
                acc[idx] = z;
                ynext[idx] = res[idx] + hcoef * z;
            } else if (emode == EM_RK_MID) {
                const float a = acc[idx] + wk * z;
                acc[idx] = a;
                ynext[idx] = res[idx] + hcoef * z;
            } else { // EM_RK_LAST
                const float a = acc[idx] + wk * z;
                ynext[idx] = res[idx] + hcoef * a;
            }
        }
    }
}

static inline void launch_gemm(const float* A, const float* B, const float* bias,
                               float* C, const float* res, float* acc, float* yn,
                               int M, int N, int K, int emode, float wk, float hc,
                               hipStream_t s)
{
    dim3 grid(N / BN, M / BM), block(256);
    hipLaunchKernelGGL(gemm_fused, grid, block, 0, s,
                       A, B, bias, C, res, acc, yn, M, N, K, emode, wk, hc);
}

extern "C" void kernel_launch(void* const* d_in, const int* in_sizes, int n_in,
                              void* d_out, int out_size, void* d_ws, size_t ws_size,
                              hipStream_t stream)
{
    (void)in_sizes; (void)n_in; (void)out_size; (void)ws_size;
    // Inputs in setup_inputs() order
    const float* x    = (const float*)d_in[0];   // [1024,256]
    const float* Wi1  = (const float*)d_in[1];   // [256,512]
    const float* bi1  = (const float*)d_in[2];   // [512]
    const float* Wi2  = (const float*)d_in[3];   // [512,512]
    const float* bi2  = (const float*)d_in[4];   // [512]
    const float* Wr   = (const float*)d_in[5];   // [256,512]
    const float* br   = (const float*)d_in[6];   // [512]
    const float* oW1  = (const float*)d_in[7];   // [5,512,1024]
    const float* ob1  = (const float*)d_in[8];   // [5,1024]
    const float* oW2  = (const float*)d_in[9];   // [5,1024,1024]
    const float* ob2  = (const float*)d_in[10];  // [5,1024]
    const float* oW3  = (const float*)d_in[11];  // [5,1024,512]
    const float* ob3  = (const float*)d_in[12];  // [5,512]
    const float* Wo1  = (const float*)d_in[13];  // [512,512]
    const float* bo1  = (const float*)d_in[14];  // [512]
    const float* Wo2  = (const float*)d_in[15];  // [512,128]
    const float* bo2  = (const float*)d_in[16];  // [128]
    float* out = (float*)d_out;                  // [1024,128]

    // Workspace layout (floats)
    float* ws = (float*)d_ws;
    const size_t SZ_H  = (size_t)BATCH * DH;   // 524288
    const size_t SZ_H2 = (size_t)BATCH * DH2;  // 1048576
    float* y    = ws;               // state [1024,512]
    float* t1   = y    + SZ_H;      // temp  [1024,512]
    float* rres = t1   + SZ_H;      // residual [1024,512]
    float* kacc = rres + SZ_H;      // RK accumulator [1024,512]
    float* ytmp = kacc + SZ_H;      // RK stage input [1024,512]
    float* a1   = ytmp + SZ_H;      // [1024,1024]
    float* a2   = a1   + SZ_H2;     // [1024,1024]

    // Input block: residual + 2-layer MLP
    launch_gemm(x, Wr, br, rres, nullptr, nullptr, nullptr,
                BATCH, DH, DIN, EM_PLAIN, 0.f, 0.f, stream);
    launch_gemm(x, Wi1, bi1, t1, nullptr, nullptr, nullptr,
                BATCH, DH, DIN, EM_TANH, 0.f, 0.f, stream);
    launch_gemm(t1, Wi2, bi2, y, rres, nullptr, nullptr,
                BATCH, DH, DH, EM_TANH_RES, 0.f, 0.f, stream);

    const float hstep = 1.0f / (float)RKSTEPS;
    for (int layer = 0; layer < NLAYERS; ++layer) {
        const float* W1 = oW1 + (size_t)layer * DH  * DH2;
        const float* b1 = ob1 + (size_t)layer * DH2;
        const float* W2 = oW2 + (size_t)layer * DH2 * DH2;
        const float* b2 = ob2 + (size_t)layer * DH2;
        const float* W3 = oW3 + (size_t)layer * DH2 * DH;
        const float* b3 = ob3 + (size_t)layer * DH;

        for (int s = 0; s < RKSTEPS; ++s) {
            // k1 from y
            launch_gemm(y, W1, b1, a1, nullptr, nullptr, nullptr,
                        BATCH, DH2, DH, EM_TANH, 0.f, 0.f, stream);
            launch_gemm(a1, W2, b2, a2, nullptr, nullptr, nullptr,
                        BATCH, DH2, DH2, EM_TANH, 0.f, 0.f, stream);
            launch_gemm(a2, W3, b3, nullptr, y, kacc, ytmp,
                        BATCH, DH, DH2, EM_RK_FIRST, 0.f, 0.5f * hstep, stream);
            // k2 from ytmp
            launch_gemm(ytmp, W1, b1, a1, nullptr, nullptr, nullptr,
                        BATCH, DH2, DH, EM_TANH, 0.f, 0.f, stream);
            launch_gemm(a1, W2, b2, a2, nullptr, nullptr, nullptr,
                        BATCH, DH2, DH2, EM_TANH, 0.f, 0.f, stream);
            launch_gemm(a2, W3, b3, nullptr, y, kacc, ytmp,
                        BATCH, DH, DH2, EM_RK_MID, 2.0f, 0.5f * hstep, stream);
            // k3 from ytmp
            launch_gemm(ytmp, W1, b1, a1, nullptr, nullptr, nullptr,
                        BATCH, DH2, DH, EM_TANH, 0.f, 0.f, stream);
            launch_gemm(a1, W2, b2, a2, nullptr, nullptr, nullptr,
                        BATCH, DH2, DH2, EM_TANH, 0.f, 0.f, stream);
            launch_gemm(a2, W3, b3, nullptr, y, kacc, ytmp,
                        BATCH, DH, DH2, EM_RK_MID, 2.0f, hstep, stream);
            // k4 from ytmp; final y update
            launch_gemm(ytmp, W1, b1, a1, nullptr, nullptr, nullptr,
                        BATCH, DH2, DH, EM_TANH, 0.f, 0.f, stream);
            launch_gemm(a1, W2, b2, a2, nullptr, nullptr, nullptr,
                        BATCH, DH2, DH2, EM_TANH, 0.f, 0.f, stream);
            launch_gemm(a2, W3, b3, nullptr, y, kacc, y,
                        BATCH, DH, DH2, EM_RK_LAST, 1.0f, hstep / 6.0f, stream);
        }
    }

    // Output MLP
    launch_gemm(y, Wo1, bo1, t1, nullptr, nullptr, nullptr,
                BATCH, DH, DH, EM_TANH, 0.f, 0.f, stream);
    launch_gemm(t1, Wo2, bo2, out, nullptr, nullptr, nullptr,
                BATCH, DOUT, DH, EM_TANH, 0.f, 0.f, stream);
}

// Round 2
// 43261.136 us; speedup vs baseline: 1.1666x; 1.1666x over previous
//
#include <hip/hip_runtime.h>
#include <hip/hip_bf16.h>
#include <math.h>

#define BATCH 1024
#define RKSTEPS 16

typedef __bf16 bf16x8 __attribute__((ext_vector_type(8)));
typedef float f32x16 __attribute__((ext_vector_type(16)));

enum { EM_PLAIN_F32=0, EM_TANH=1, EM_TANH_RES=2, EM_RK_FIRST=3, EM_RK_MID=4, EM_RK_LAST=5, EM_TANH_OUT=6 };

__device__ __forceinline__ unsigned short f2bf(float f){
    unsigned int u = __float_as_uint(f);
    u += 0x7fffu + ((u >> 16) & 1u);           // round-to-nearest-even
    return (unsigned short)(u >> 16);
}
__device__ __forceinline__ float bf2f(unsigned short h){
    return __uint_as_float(((unsigned int)h) << 16);
}

// ---- preprocessing: split x (row-major, no transpose) ----
__global__ __launch_bounds__(256) void xsplit(const float* __restrict__ src,
                                              unsigned short* __restrict__ h,
                                              unsigned short* __restrict__ l, int n){
    int i = blockIdx.x * 256 + threadIdx.x;
    if (i < n){
        float v = src[i];
        unsigned short hh = f2bf(v);
        h[i] = hh;
        l[i] = f2bf(v - bf2f(hh));
    }
}

// ---- preprocessing: transpose W[K][N] -> Th/Tl[N][K] bf16 hi/lo ----
__global__ __launch_bounds__(256) void wsplit_t(const float* __restrict__ W,
                                                unsigned short* __restrict__ Th,
                                                unsigned short* __restrict__ Tl,
                                                int K, int N){
    __shared__ float tile[32][33];
    const int k0 = blockIdx.x * 32;
    const int n0 = blockIdx.y * 32;
    const int t = threadIdx.x;
    const int r = t >> 3;          // 0..31
    const int c4 = (t & 7) * 4;    // 0..28
    const float4 v = *(const float4*)&W[(size_t)(k0 + r) * N + n0 + c4];
    tile[r][c4+0] = v.x; tile[r][c4+1] = v.y; tile[r][c4+2] = v.z; tile[r][c4+3] = v.w;
    __syncthreads();
    ushort4 hh, ll;
    #pragma unroll
    for (int j = 0; j < 4; ++j){
        float x = tile[c4 + j][r];
        unsigned short hb = f2bf(x);
        ((unsigned short*)&hh)[j] = hb;
        ((unsigned short*)&ll)[j] = f2bf(x - bf2f(hb));
    }
    *(ushort4*)&Th[(size_t)(n0 + r) * K + k0 + c4] = hh;
    *(ushort4*)&Tl[(size_t)(n0 + r) * K + k0 + c4] = ll;
}

// ---- main 3-pass split-bf16 MFMA GEMM with fused epilogues ----
// C[M,N] = epi(A[M,K] @ B[K,N] + bias), B given transposed [N][K].
// A given as hi/lo bf16 planes [M][K]; B as hi/lo bf16 planes [N][K].
__global__ __launch_bounds__(128) void gemm3p(
    const unsigned short* __restrict__ Ah, const unsigned short* __restrict__ Al,
    const unsigned short* __restrict__ Bh, const unsigned short* __restrict__ Bl,
    const float* __restrict__ bias,
    int M, int N, int K, int mode, float wk, float hc,
    unsigned short* __restrict__ outh, unsigned short* __restrict__ outl,
    float* outf, const float* res32, float* kacc32)
{
    __shared__ unsigned short Ash[32][72];   // +8 pad: uniform superbank spread
    __shared__ unsigned short Asl[32][72];
    __shared__ unsigned short Bsh[64][72];
    __shared__ unsigned short Bsl[64][72];

    const int tid  = threadIdx.x;
    const int lane = tid & 63;
    const int w    = tid >> 6;          // wave 0/1 -> col halves
    const int m0   = blockIdx.y * 32;
    const int n0   = blockIdx.x * 64;

    f32x16 accA, accB;
    #pragma unroll
    for (int i = 0; i < 16; ++i){ accA[i] = 0.f; accB[i] = 0.f; }

    uint4 rAh[2], rAl[2], rBh[4], rBl[4];

    auto stage_load = [&](int k0){
        #pragma unroll
        for (int p = 0; p < 2; ++p){
            int id = p * 128 + tid; int r = id >> 3; int c = (id & 7) * 8;
            size_t off = (size_t)(m0 + r) * K + k0 + c;
            rAh[p] = *(const uint4*)&Ah[off];
            rAl[p] = *(const uint4*)&Al[off];
        }
        #pragma unroll
        for (int p = 0; p < 4; ++p){
            int id = p * 128 + tid; int r = id >> 3; int c = (id & 7) * 8;
            size_t off = (size_t)(n0 + r) * K + k0 + c;
            rBh[p] = *(const uint4*)&Bh[off];
            rBl[p] = *(const uint4*)&Bl[off];
        }
    };
    auto stage_write = [&](){
        #pragma unroll
        for (int p = 0; p < 2; ++p){
            int id = p * 128 + tid; int r = id >> 3; int c = (id & 7) * 8;
            *(uint4*)&Ash[r][c] = rAh[p];
            *(uint4*)&Asl[r][c] = rAl[p];
        }
        #pragma unroll
        for (int p = 0; p < 4; ++p){
            int id = p * 128 + tid; int r = id >> 3; int c = (id & 7) * 8;
            *(uint4*)&Bsh[r][c] = rBh[p];
            *(uint4*)&Bsl[r][c] = rBl[p];
        }
    };

    stage_load(0);
    stage_write();
    __syncthreads();

    const int arow = lane & 31;
    const int brow = w * 32 + (lane & 31);
    const int g8   = (lane >> 5) * 8;

    for (int k0 = 0; k0 < K; k0 += 64){
        const bool more = (k0 + 64) < K;
        if (more) stage_load(k0 + 64);            // overlap global latency with MFMA
        #pragma unroll
        for (int kc = 0; kc < 4; ++kc){
            const int koff = kc * 16 + g8;
            bf16x8 a_h = *(const bf16x8*)&Ash[arow][koff];
            bf16x8 a_l = *(const bf16x8*)&Asl[arow][koff];
            bf16x8 b_h = *(const bf16x8*)&Bsh[brow][koff];
            bf16x8 b_l = *(const bf16x8*)&Bsl[brow][koff];
            accA = __builtin_amdgcn_mfma_f32_32x32x16_bf16(a_h, b_h, accA, 0, 0, 0);
            accB = __builtin_amdgcn_mfma_f32_32x32x16_bf16(a_h, b_l, accB, 0, 0, 0);
            accB = __builtin_amdgcn_mfma_f32_32x32x16_bf16(a_l, b_h, accB, 0, 0, 0);
        }
        if (more){
            __syncthreads();
            stage_write();
            __syncthreads();
        }
    }

    // epilogue: C/D layout col=lane&31, row=(r&3)+8*(r>>2)+4*(lane>>5)
    const int col = n0 + w * 32 + (lane & 31);
    const float bc = bias[col];
    const int g4 = (lane >> 5) * 4;
    #pragma unroll
    for (int r = 0; r < 16; ++r){
        const int row = m0 + (r & 3) + 8 * (r >> 2) + g4;
        const size_t idx = (size_t)row * N + col;
        float z = accA[r] + accB[r] + bc;
        if (mode == EM_PLAIN_F32){
            outf[idx] = z;
        } else if (mode == EM_TANH){
            float t = tanhf(z);
            unsigned short hh = f2bf(t);
            outh[idx] = hh; outl[idx] = f2bf(t - bf2f(hh));
        } else if (mode == EM_TANH_RES){
            float t = tanhf(z) + res32[idx];
            outf[idx] = t;
            unsigned short hh = f2bf(t);
            outh[idx] = hh; outl[idx] = f2bf(t - bf2f(hh));
        } else if (mode == EM_RK_FIRST){
            kacc32[idx] = z;
            float yt = res32[idx] + hc * z;
            unsigned short hh = f2bf(yt);
            outh[idx] = hh; outl[idx] = f2bf(yt - bf2f(hh));
        } else if (mode == EM_RK_MID){
            kacc32[idx] += wk * z;
            float yt = res32[idx] + hc * z;
            unsigned short hh = f2bf(yt);
            outh[idx] = hh; outl[idx] = f2bf(yt - bf2f(hh));
        } else if (mode == EM_RK_LAST){
            float ynew = res32[idx] + hc * (kacc32[idx] + z);
            outf[idx] = ynew;
            unsigned short hh = f2bf(ynew);
            outh[idx] = hh; outl[idx] = f2bf(ynew - bf2f(hh));
        } else { // EM_TANH_OUT
            outf[idx] = tanhf(z);
        }
    }
}

extern "C" void kernel_launch(void* const* d_in, const int* in_sizes, int n_in,
                              void* d_out, int out_size, void* d_ws, size_t ws_size,
                              hipStream_t stream)
{
    (void)in_sizes; (void)n_in; (void)out_size; (void)ws_size;
    const float* x   = (const float*)d_in[0];
    const float* Wi1 = (const float*)d_in[1];
    const float* bi1 = (const float*)d_in[2];
    const float* Wi2 = (const float*)d_in[3];
    const float* bi2 = (const float*)d_in[4];
    const float* Wr  = (const float*)d_in[5];
    const float* br  = (const float*)d_in[6];
    const float* oW1 = (const float*)d_in[7];
    const float* ob1 = (const float*)d_in[8];
    const float* oW2 = (const float*)d_in[9];
    const float* ob2 = (const float*)d_in[10];
    const float* oW3 = (const float*)d_in[11];
    const float* ob3 = (const float*)d_in[12];
    const float* Wo1 = (const float*)d_in[13];
    const float* bo1 = (const float*)d_in[14];
    const float* Wo2 = (const float*)d_in[15];
    const float* bo2 = (const float*)d_in[16];
    float* out = (float*)d_out;

    typedef unsigned short us;
    char* p = (char*)d_ws;
    auto alloc = [&](size_t bytes)->char*{ char* r = p; p += (bytes + 255) & ~(size_t)255; return r; };

    // bf16 hi/lo planes
    us* xh = (us*)alloc(1024*256*2);  us* xl = (us*)alloc(1024*256*2);
    us* Wi1th = (us*)alloc(512*256*2);  us* Wi1tl = (us*)alloc(512*256*2);
    us* Wi2th = (us*)alloc(512*512*2);  us* Wi2tl = (us*)alloc(512*512*2);
    us* Wrth  = (us*)alloc(512*256*2);  us* Wrtl  = (us*)alloc(512*256*2);
    us* oW1th = (us*)alloc(5ull*1024*512*2);  us* oW1tl = (us*)alloc(5ull*1024*512*2);
    us* oW2th = (us*)alloc(5ull*1024*1024*2); us* oW2tl = (us*)alloc(5ull*1024*1024*2);
    us* oW3th = (us*)alloc(5ull*512*1024*2);  us* oW3tl = (us*)alloc(5ull*512*1024*2);
    us* Wo1th = (us*)alloc(512*512*2);  us* Wo1tl = (us*)alloc(512*512*2);
    us* Wo2th = (us*)alloc(128*512*2);  us* Wo2tl = (us*)alloc(128*512*2);
    us* t1h = (us*)alloc(1024ull*1024*2); us* t1l = (us*)alloc(1024ull*1024*2);
    us* a2h = (us*)alloc(1024ull*1024*2); us* a2l = (us*)alloc(1024ull*1024*2);
    us* yh  = (us*)alloc(1024ull*512*2);  us* yl  = (us*)alloc(1024ull*512*2);
    us* yth = (us*)alloc(1024ull*512*2);  us* ytl = (us*)alloc(1024ull*512*2);
    // fp32 state
    float* y32  = (float*)alloc(1024ull*512*4);
    float* kacc = (float*)alloc(1024ull*512*4);
    float* rres = (float*)alloc(1024ull*512*4);

    // ---- preprocessing ----
    hipLaunchKernelGGL(xsplit, dim3(1024), dim3(256), 0, stream, x, xh, xl, 1024*256);
    auto WS = [&](const float* W, us* th, us* tl, int K, int N){
        hipLaunchKernelGGL(wsplit_t, dim3(K/32, N/32), dim3(256), 0, stream, W, th, tl, K, N);
    };
    WS(Wi1, Wi1th, Wi1tl, 256, 512);
    WS(Wi2, Wi2th, Wi2tl, 512, 512);
    WS(Wr,  Wrth,  Wrtl,  256, 512);
    for (int L = 0; L < 5; ++L){
        WS(oW1 + (size_t)L*512*1024,  oW1th + (size_t)L*1024*512,  oW1tl + (size_t)L*1024*512,  512, 1024);
        WS(oW2 + (size_t)L*1024*1024, oW2th + (size_t)L*1024*1024, oW2tl + (size_t)L*1024*1024, 1024, 1024);
        WS(oW3 + (size_t)L*1024*512,  oW3th + (size_t)L*512*1024,  oW3tl + (size_t)L*512*1024,  1024, 512);
    }
    WS(Wo1, Wo1th, Wo1tl, 512, 512);
    WS(Wo2, Wo2th, Wo2tl, 512, 128);

    auto G = [&](const us* ah, const us* al, const us* bh, const us* bl,
                 const float* bias, int N, int K, int mode, float wkv, float hcv,
                 us* oh, us* ol, float* of, const float* rs, float* ka){
        dim3 grid(N/64, BATCH/32);
        hipLaunchKernelGGL(gemm3p, grid, dim3(128), 0, stream,
                           ah, al, bh, bl, bias, BATCH, N, K, mode, wkv, hcv, oh, ol, of, rs, ka);
    };

    // input block
    G(xh, xl, Wrth, Wrtl, br, 512, 256, EM_PLAIN_F32, 0.f, 0.f, nullptr, nullptr, rres, nullptr, nullptr);
    G(xh, xl, Wi1th, Wi1tl, bi1, 512, 256, EM_TANH, 0.f, 0.f, t1h, t1l, nullptr, nullptr, nullptr);
    G(t1h, t1l, Wi2th, Wi2tl, bi2, 512, 512, EM_TANH_RES, 0.f, 0.f, yh, yl, y32, rres, nullptr);

    const float hs = 1.0f / (float)RKSTEPS;
    for (int L = 0; L < 5; ++L){
        const us* W1h = oW1th + (size_t)L*1024*512;  const us* W1l = oW1tl + (size_t)L*1024*512;
        const us* W2h = oW2th + (size_t)L*1024*1024; const us* W2l = oW2tl + (size_t)L*1024*1024;
        const us* W3h = oW3th + (size_t)L*512*1024;  const us* W3l = oW3tl + (size_t)L*512*1024;
        const float* b1 = ob1 + (size_t)L*1024;
        const float* b2 = ob2 + (size_t)L*1024;
        const float* b3 = ob3 + (size_t)L*512;
        for (int s = 0; s < RKSTEPS; ++s){
            // k1 (from y)
            G(yh, yl, W1h, W1l, b1, 1024, 512,  EM_TANH, 0.f, 0.f, t1h, t1l, nullptr, nullptr, nullptr);
            G(t1h, t1l, W2h, W2l, b2, 1024, 1024, EM_TANH, 0.f, 0.f, a2h, a2l, nullptr, nullptr, nullptr);
            G(a2h, a2l, W3h, W3l, b3, 512, 1024, EM_RK_FIRST, 0.f, 0.5f*hs, yth, ytl, nullptr, y32, kacc);
            // k2 (from ytmp)
            G(yth, ytl, W1h, W1l, b1, 1024, 512,  EM_TANH, 0.f, 0.f, t1h, t1l, nullptr, nullptr, nullptr);
            G(t1h, t1l, W2h, W2l, b2, 1024, 1024, EM_TANH, 0.f, 0.f, a2h, a2l, nullptr, nullptr, nullptr);
            G(a2h, a2l, W3h, W3l, b3, 512, 1024, EM_RK_MID, 2.f, 0.5f*hs, yth, ytl, nullptr, y32, kacc);
            // k3
            G(yth, ytl, W1h, W1l, b1, 1024, 512,  EM_TANH, 0.f, 0.f, t1h, t1l, nullptr, nullptr, nullptr);
            G(t1h, t1l, W2h, W2l, b2, 1024, 1024, EM_TANH, 0.f, 0.f, a2h, a2l, nullptr, nullptr, nullptr);
            G(a2h, a2l, W3h, W3l, b3, 512, 1024, EM_RK_MID, 2.f, hs, yth, ytl, nullptr, y32, kacc);
            // k4 -> y update
            G(yth, ytl, W1h, W1l, b1, 1024, 512,  EM_TANH, 0.f, 0.f, t1h, t1l, nullptr, nullptr, nullptr);
            G(t1h, t1l, W2h, W2l, b2, 1024, 1024, EM_TANH, 0.f, 0.f, a2h, a2l, nullptr, nullptr, nullptr);
            G(a2h, a2l, W3h, W3l, b3, 512, 1024, EM_RK_LAST, 1.f, hs/6.f, yh, yl, y32, y32, kacc);
        }
    }

    // output MLP
    G(yh, yl, Wo1th, Wo1tl, bo1, 512, 512, EM_TANH, 0.f, 0.f, t1h, t1l, nullptr, nullptr, nullptr);
    G(t1h, t1l, Wo2th, Wo2tl, bo2, 128, 512, EM_TANH_OUT, 0.f, 0.f, nullptr, nullptr, out, nullptr, nullptr);
}